// Round 5
// baseline (1479.641 us; speedup 1.0000x reference)
//
#include <hip/hip_runtime.h>

// Swin window attention, fused persistent-block design (R5 = spill fix).
// Shapes: B=64, RES=56, DIMS=192, HEADS=6, HD=32, WS=7, N=49, nW=64, SHIFT=3.
// Grid = 256 blocks (1/CU), each block persists over 16 windows (batch b constant
// per block). Block = 768 threads (12 waves, 3/SIMD, LDS-capped at 1 block/CU).
//
// R5 fix: R4 hoisted bm[2][4][4] (32 VGPR) + coord arrays (16) + px (16) past
// the 84-VGPR allocation -> compiler spilled to SCRATCH; scratch re-reads in the
// phase-3 inner loop missed L2 (10 MB/XCD working set > 4 MB) -> FETCH 2.4 GB,
// 3x slowdown. R5 shrinks hoisted state: bmadd[4][4] keeps only the mask term
// (0/-1000/-inf, 16 regs); bias re-loaded from biasx inline per head (L2-hot,
// proven cheap in R1); coord arrays recomputed inline per use site.
//
// R4 fix retained: Q/K pad-token rows (>=49) zeroed at phase-2 store, so the
// -inf mask add never meets NaN/Inf garbage.
//
// Structure (R2): all epilogues vectorized via MFMA operand-role swaps; LDS
// layouts: [tok][d] row-major for X/Q/K/O, VT[d][key], P[q][key]:
//  - Q/K proj: D = W^T·X^T -> short4v LDS stores.
//  - QK^T swapped: mfma(K,Q) = S^T -> lane holds 16 scores of ONE query;
//    softmax reduce = 2 shfl_xor; P write = 4 short4v.
//  - PV swapped: mfma(V^T, P^T) = O^T -> short4v O stores.
//  - out-proj swapped: mfma(Wo^T, O^T) -> float4 global stores.
//  - Persistent: next window's X global-loaded to regs during ph3, written to
//    LDS during ph4; X/O and P ping-pong between two buffers. 3 barriers/window.
//
// Layout facts used (verified per guide):
//   A-frag: lane holds A[m=lane&15][k=(lane>>4)*8 + j], j=0..7 (16B contig)
//   B-frag: lane holds B[k=(lane>>4)*8 + j][n=lane&15]
//   C/D   : lane holds D[m=(lane>>4)*4 + r][n=lane&15], r=0..3
// Mask quirk: reference repeats mask by batch (scores[b*64+w] gets mask[b]).

typedef __attribute__((ext_vector_type(8))) short bf16x8;
typedef __attribute__((ext_vector_type(4))) short short4v;
typedef __attribute__((ext_vector_type(4))) float f32x4;

__device__ __forceinline__ short f2bf(float x) {
  unsigned u = __builtin_bit_cast(unsigned, x);
  u += 0x7fffu + ((u >> 16) & 1u);   // RNE
  return (short)(u >> 16);
}

// ---------------- prep: weight transpose->bf16, bias expansion ----------------
__global__ void prep_kernel(const float* __restrict__ wq, const float* __restrict__ wk,
                            const float* __restrict__ wv, const float* __restrict__ wo,
                            const float* __restrict__ table,
                            short* __restrict__ wT, float* __restrict__ biasx) {
  int tid = blockIdx.x * 256 + threadIdx.x;
  if (tid < 4 * 36864) {
    int mat = tid / 36864, rem = tid % 36864;
    int k = rem / 192, n = rem % 192;
    const float* w = (mat == 0) ? wq : (mat == 1) ? wk : (mat == 2) ? wv : wo;
    wT[mat * 36864 + n * 192 + k] = f2bf(w[k * 192 + n]);
  }
  if (tid < 6 * 2401) {
    int h = tid / 2401, rem = tid % 2401;
    int q = rem / 49, k = rem % 49;
    int idx = ((q / 7) - (k / 7) + 6) * 13 + ((q % 7) - (k % 7) + 6);
    biasx[tid] = table[idx * 6 + h];
  }
}

// ---------------- main fused persistent kernel ----------------
__launch_bounds__(768, 3)
__global__ void swin_attn_kernel(const float* __restrict__ x,
                                 const short* __restrict__ wT,
                                 const float* __restrict__ biasx,
                                 const float* __restrict__ bq, const float* __restrict__ bk,
                                 const float* __restrict__ bv, const float* __restrict__ bo,
                                 float* __restrict__ out) {
  extern __shared__ short smem[];
  short* bufA = smem;            // 13824: X/O (even windows) or P strips (odd)
  short* bufB = smem + 13824;    // 13824: P strips (even windows) or X/O (odd)
  short* s_q  = smem + 27648;    // 64 x 200
  short* s_k  = smem + 40448;    // 64 x 200
  short* s_vt = smem + 53248;    // 192 x 72 (V transposed: [d][key])
  // total = 67072 shorts = 134144 B (1 block/CU)

  const int tid  = threadIdx.x;
  const int w    = tid >> 6;       // wave id 0..11
  const int lane = tid & 63;
  const int quad = lane >> 4;
  const int l15  = lane & 15;

  const int p   = blockIdx.x;       // persistent block id: windows 16p..16p+15
  const int b   = p >> 2;           // batch (constant per block)
  const int mwh = b >> 3, mww = b & 7;   // mask window coords (reference quirk!)

  const int rt = w & 3;   // token/query/key row-tile owned by this wave
  const int g  = w >> 2;  // dout-third (ph2/ph4) == head-pair (ph3)

  const f32x4 zero4 = {0.f, 0.f, 0.f, 0.f};
  const float NEGINF = -__builtin_inff();
  const float SCALE = 0.17677669529663687f;  // 1/sqrt(32)

  const bool has4 = (tid < 48);   // 49*48 = 2352 = 768*3 + 48

  // token owned in ph2 Q/K store and ph4 (swapped layouts): rt*16 + l15
  const int token = rt * 16 + l15;
  const bool tokv = (token < 49);

  // ---- hoisted phase-3 mask-add term (loop-invariant; 16 regs only) ----
  // bmadd[mt][r] in {0, -1000, -inf} for query = rt*16+l15, key = mt*16+quad*4+r.
  const int qc  = tokv ? token : 48;
  const int qth = qc / 7, qtw = qc - qth * 7;
  const int cq  = ((mwh == 7) ? (1 + (qth >= 4)) : 0) * 3
                + ((mww == 7) ? (1 + (qtw >= 4)) : 0);
  float bmadd[4][4];
#pragma unroll
  for (int mt = 0; mt < 4; ++mt) {
#pragma unroll
    for (int r = 0; r < 4; ++r) {
      int key = mt * 16 + quad * 4 + r;
      if (key > 48) {
        bmadd[mt][r] = NEGINF;
      } else {
        int kth = key / 7, ktw = key - kth * 7;
        int ck = ((mwh == 7) ? (1 + (kth >= 4)) : 0) * 3
               + ((mww == 7) ? (1 + (ktw >= 4)) : 0);
        bmadd[mt][r] = (ck == cq) ? 0.f : -1000.f;
      }
    }
  }

  // ---- hoisted phase-4 token coords (3 regs) ----
  const int tt  = tokv ? token : 0;
  const int tth = tt / 7, ttw = tt - tth * 7;

  // ---- prologue: load window 0's X -> bufA (coords computed inline) ----
  {
    const int wi0 = (p & 3) * 16;
    const int hb = (wi0 >> 3) * 7 + 3, wb = (wi0 & 7) * 7 + 3;
    for (int i = tid; i < 2352; i += 768) {
      int t = i / 48, c4 = i - t * 48;
      int th = t / 7, tw = t - th * 7;
      int gh = hb + th; if (gh >= 56) gh -= 56;
      int gw = wb + tw; if (gw >= 56) gw -= 56;
      float4 v = *(const float4*)(x + (((b * 56 + gh) * 56 + gw) * 192 + c4 * 4));
      short4v s;
      s[0] = f2bf(v.x); s[1] = f2bf(v.y); s[2] = f2bf(v.z); s[3] = f2bf(v.w);
      *(short4v*)(bufA + t * 200 + c4 * 4) = s;
    }
  }
  __syncthreads();

  float4 px0, px1, px2, px3;

#pragma unroll 1
  for (int win = 0; win < 16; ++win) {
    short* xw   = (win & 1) ? bufB : bufA;   // X (ph2), then O (ph3/ph4)
    short* pbuf = (win & 1) ? bufA : bufB;   // P strips (ph3), then next X (ph4)
    const int wi  = (p & 3) * 16 + win;
    const int wwh = wi >> 3, www = wi & 7;

    // ---- phase 2: QKV projections ----
    bf16x8 xf[6];
#pragma unroll
    for (int ks = 0; ks < 6; ++ks)
      xf[ks] = *(const bf16x8*)(xw + (rt * 16 + l15) * 200 + ks * 32 + quad * 8);

    // Q, K swapped: D[m=dout][n=token] = W^T · X^T -> short4v stores.
    // Pad tokens (>=49) store 0 (X rows 49..63 are garbage; keep ph3 NaN-free).
#pragma unroll
    for (int mat = 0; mat < 2; ++mat) {
      const short* wt = wT + mat * 36864;
      const float* bp = mat ? bk : bq;
      short* dst = mat ? s_k : s_q;
#pragma unroll
      for (int j = 0; j < 4; ++j) {
        const int dbase = (g * 4 + j) * 16;
        const short* wrow = wt + (dbase + l15) * 192;
        f32x4 acc = zero4;
#pragma unroll
        for (int ks = 0; ks < 6; ++ks) {
          bf16x8 wfr = *(const bf16x8*)(wrow + ks * 32 + quad * 8);
          acc = __builtin_amdgcn_mfma_f32_16x16x32_bf16(wfr, xf[ks], acc, 0, 0, 0);
        }
        const float4 b4 = *(const float4*)(bp + dbase + quad * 4);
        short4v st;
        st[0] = f2bf(tokv ? acc[0] + b4.x : 0.f);
        st[1] = f2bf(tokv ? acc[1] + b4.y : 0.f);
        st[2] = f2bf(tokv ? acc[2] + b4.z : 0.f);
        st[3] = f2bf(tokv ? acc[3] + b4.w : 0.f);
        *(short4v*)(dst + (rt * 16 + l15) * 200 + dbase + quad * 4) = st;
      }
    }
    // V unswapped: D[m=key][n=dout] -> short4v stores into VT[d][key].
    {
      const short* wt = wT + 2 * 36864;
#pragma unroll
      for (int j = 0; j < 4; ++j) {
        const int dbase = (g * 4 + j) * 16;
        const short* wrow = wt + (dbase + l15) * 192;
        f32x4 acc = zero4;
#pragma unroll
        for (int ks = 0; ks < 6; ++ks) {
          bf16x8 wfr = *(const bf16x8*)(wrow + ks * 32 + quad * 8);
          acc = __builtin_amdgcn_mfma_f32_16x16x32_bf16(xf[ks], wfr, acc, 0, 0, 0);
        }
        const float bvv = bv[dbase + l15];
        short4v st;
#pragma unroll
        for (int r = 0; r < 4; ++r) {
          int key = rt * 16 + quad * 4 + r;
          st[r] = f2bf((key < 49) ? (acc[r] + bvv) : 0.f);   // zero pad keys
        }
        *(short4v*)(s_vt + (dbase + l15) * 72 + rt * 16 + quad * 4) = st;
      }
    }
    __syncthreads();   // B1: QKV ready; X dead

    // ---- issue next window's X loads (latency hides under phase 3) ----
    if (win < 15) {
      const int wi2 = wi + 1;
      const int hb = (wi2 >> 3) * 7 + 3, wb = (wi2 & 7) * 7 + 3;
      {
        int i = tid;
        int t = i / 48, c4 = i - t * 48;
        int th = t / 7, tw = t - th * 7;
        int gh = hb + th; if (gh >= 56) gh -= 56;
        int gw = wb + tw; if (gw >= 56) gw -= 56;
        px0 = *(const float4*)(x + (((b * 56 + gh) * 56 + gw) * 192 + c4 * 4));
      }
      {
        int i = tid + 768;
        int t = i / 48, c4 = i - t * 48;
        int th = t / 7, tw = t - th * 7;
        int gh = hb + th; if (gh >= 56) gh -= 56;
        int gw = wb + tw; if (gw >= 56) gw -= 56;
        px1 = *(const float4*)(x + (((b * 56 + gh) * 56 + gw) * 192 + c4 * 4));
      }
      {
        int i = tid + 1536;
        int t = i / 48, c4 = i - t * 48;
        int th = t / 7, tw = t - th * 7;
        int gh = hb + th; if (gh >= 56) gh -= 56;
        int gw = wb + tw; if (gw >= 56) gw -= 56;
        px2 = *(const float4*)(x + (((b * 56 + gh) * 56 + gw) * 192 + c4 * 4));
      }
      if (has4) {
        int i = tid + 2304;
        int t = i / 48, c4 = i - t * 48;
        int th = t / 7, tw = t - th * 7;
        int gh = hb + th; if (gh >= 56) gh -= 56;
        int gw = wb + tw; if (gw >= 56) gw -= 56;
        px3 = *(const float4*)(x + (((b * 56 + gh) * 56 + gw) * 192 + c4 * 4));
      }
    }

    // ---- phase 3: attention (wave = query-tile rt x head-pair g) ----
    short* myp = pbuf + w * 1152;   // wave-private 16x72 P strip
#pragma unroll
    for (int hh = 0; hh < 2; ++hh) {
      const int h = g * 2 + hh;
      const int d0 = h * 32;
      const float* bx = biasx + h * 2401 + qc * 49;
      // swapped QK^T: S^T[key][query] = mfma(A=K rows, B=Q^T)
      bf16x8 qf = *(const bf16x8*)(s_q + (rt * 16 + l15) * 200 + d0 + quad * 8);
      float sv[4][4];
#pragma unroll
      for (int mt = 0; mt < 4; ++mt) {
        bf16x8 kf = *(const bf16x8*)(s_k + (mt * 16 + l15) * 200 + d0 + quad * 8);
        f32x4 s = __builtin_amdgcn_mfma_f32_16x16x32_bf16(kf, qf, zero4, 0, 0, 0);
#pragma unroll
        for (int r = 0; r < 4; ++r) {
          // clamp bias addr for pad keys (mt==3 only); value is irrelevant there
          // because bmadd = -inf and all operands stay finite.
          int key = mt * 16 + quad * 4 + r;
          int kc = (mt < 3) ? key : (((quad * 4 + r) == 0) ? 48 : 0);
          sv[mt][r] = s[r] * SCALE + bx[kc] + bmadd[mt][r];
        }
      }
      // softmax for query l15: 16 lane-local values, reduce across quads (2 shfl)
      float mx = sv[0][0];
#pragma unroll
      for (int mt = 0; mt < 4; ++mt)
#pragma unroll
        for (int r = 0; r < 4; ++r) mx = fmaxf(mx, sv[mt][r]);
      mx = fmaxf(mx, __shfl_xor(mx, 16));
      mx = fmaxf(mx, __shfl_xor(mx, 32));
      float s0 = 0.f;
#pragma unroll
      for (int mt = 0; mt < 4; ++mt)
#pragma unroll
        for (int r = 0; r < 4; ++r) {
          float e = __expf(sv[mt][r] - mx);
          sv[mt][r] = e;
          s0 += e;
        }
      s0 += __shfl_xor(s0, 16);
      s0 += __shfl_xor(s0, 32);
      const float inv = 1.0f / s0;   // normalization folded into O epilogue
      // P -> LDS (unnormalized, bf16). Same-wave LDS RAW: DS in wave order.
#pragma unroll
      for (int mt = 0; mt < 4; ++mt) {
        short4v st;
#pragma unroll
        for (int r = 0; r < 4; ++r) st[r] = f2bf(sv[mt][r]);
        *(short4v*)(myp + l15 * 72 + mt * 16 + quad * 4) = st;
      }
      // swapped PV: O^T[d][query] = mfma(A=V^T rows, B=P^T)
#pragma unroll
      for (int mt2 = 0; mt2 < 2; ++mt2) {
        f32x4 o = zero4;
#pragma unroll
        for (int ks = 0; ks < 2; ++ks) {
          bf16x8 vfr = *(const bf16x8*)(s_vt + (d0 + mt2 * 16 + l15) * 72 + ks * 32 + quad * 8);
          bf16x8 pfr = *(const bf16x8*)(myp + l15 * 72 + ks * 32 + quad * 8);
          o = __builtin_amdgcn_mfma_f32_16x16x32_bf16(vfr, pfr, o, 0, 0, 0);
        }
        short4v st;
#pragma unroll
        for (int r = 0; r < 4; ++r) st[r] = f2bf(o[r] * inv);
        *(short4v*)(xw + (rt * 16 + l15) * 200 + d0 + mt2 * 16 + quad * 4) = st;
      }
    }
    __syncthreads();   // B2: O ready (cross-wave); P strips dead

    // ---- phase 4: out projection (swapped) + next-X LDS write ----
    bf16x8 ao[6];
#pragma unroll
    for (int ks = 0; ks < 6; ++ks)
      ao[ks] = *(const bf16x8*)(xw + (rt * 16 + l15) * 200 + ks * 32 + quad * 8);

    // write next window's X into pbuf (P strips dead after B2; overlaps ph4 MFMAs)
    if (win < 15) {
      {
        int i = tid;        int t = i / 48, c4 = i - t * 48;
        short4v s;
        s[0] = f2bf(px0.x); s[1] = f2bf(px0.y); s[2] = f2bf(px0.z); s[3] = f2bf(px0.w);
        *(short4v*)(pbuf + t * 200 + c4 * 4) = s;
      }
      {
        int i = tid + 768;  int t = i / 48, c4 = i - t * 48;
        short4v s;
        s[0] = f2bf(px1.x); s[1] = f2bf(px1.y); s[2] = f2bf(px1.z); s[3] = f2bf(px1.w);
        *(short4v*)(pbuf + t * 200 + c4 * 4) = s;
      }
      {
        int i = tid + 1536; int t = i / 48, c4 = i - t * 48;
        short4v s;
        s[0] = f2bf(px2.x); s[1] = f2bf(px2.y); s[2] = f2bf(px2.z); s[3] = f2bf(px2.w);
        *(short4v*)(pbuf + t * 200 + c4 * 4) = s;
      }
      if (has4) {
        int i = tid + 2304; int t = i / 48, c4 = i - t * 48;
        short4v s;
        s[0] = f2bf(px3.x); s[1] = f2bf(px3.y); s[2] = f2bf(px3.z); s[3] = f2bf(px3.w);
        *(short4v*)(pbuf + t * 200 + c4 * 4) = s;
      }
    }

    // out^T[col][token] = mfma(A=Wo^T rows, B=O^T) -> float4 global stores
    int rowbase = 0;
    if (tokv) {
      int gh = wwh * 7 + tth + 3; if (gh >= 56) gh -= 56;
      int gw = www * 7 + ttw + 3; if (gw >= 56) gw -= 56;
      rowbase = ((b * 56 + gh) * 56 + gw) * 192;
    }
    const short* wto = wT + 3 * 36864;
#pragma unroll
    for (int j = 0; j < 4; ++j) {
      const int cbase = (g * 4 + j) * 16;
      const short* wrow = wto + (cbase + l15) * 192;
      f32x4 acc = zero4;
#pragma unroll
      for (int ks = 0; ks < 6; ++ks) {
        bf16x8 wfr = *(const bf16x8*)(wrow + ks * 32 + quad * 8);
        acc = __builtin_amdgcn_mfma_f32_16x16x32_bf16(wfr, ao[ks], acc, 0, 0, 0);
      }
      const float4 b4 = *(const float4*)(bo + cbase + quad * 4);
      if (tokv) {
        float4 v;
        v.x = acc[0] + b4.x; v.y = acc[1] + b4.y;
        v.z = acc[2] + b4.z; v.w = acc[3] + b4.w;
        *(float4*)(out + rowbase + cbase + quad * 4) = v;
      }
    }
    __syncthreads();   // B3: next-X ready; this window's LDS reads all done
  }
}

extern "C" void kernel_launch(void* const* d_in, const int* in_sizes, int n_in,
                              void* d_out, int out_size, void* d_ws, size_t ws_size,
                              hipStream_t stream) {
  const float* x     = (const float*)d_in[0];
  const float* table = (const float*)d_in[1];
  const float* wq    = (const float*)d_in[2];
  const float* bq    = (const float*)d_in[3];
  const float* wk    = (const float*)d_in[4];
  const float* bk    = (const float*)d_in[5];
  const float* wv    = (const float*)d_in[6];
  const float* bv    = (const float*)d_in[7];
  const float* wo    = (const float*)d_in[8];
  const float* bo    = (const float*)d_in[9];
  float* out = (float*)d_out;

  short* wT    = (short*)d_ws;                       // 294912 B
  float* biasx = (float*)((char*)d_ws + 294912);     // 57624 B

  prep_kernel<<<576, 256, 0, stream>>>(wq, wk, wv, wo, table, wT, biasx);

  const int smem_bytes = 67072 * 2;  // 134144
  (void)hipFuncSetAttribute(reinterpret_cast<const void*>(swin_attn_kernel),
                            hipFuncAttributeMaxDynamicSharedMemorySize, smem_bytes);
  swin_attn_kernel<<<256, 768, smem_bytes, stream>>>(x, wT, biasx, bq, bk, bv, bo, out);
}

// Round 6
// 838.532 us; speedup vs baseline: 1.7646x; 1.7646x over previous
//
#include <hip/hip_runtime.h>

// Swin window attention, fused one-window-per-block (R6).
// Shapes: B=64, RES=56, DIMS=192, HEADS=6, HD=32, WS=7, N=49, nW=64, SHIFT=3.
// Grid = 4096 blocks (1 window each, R1's proven-cheap-traffic config: 77 MB
// FETCH). Block = 768 threads (12 waves, 3/SIMD, LDS caps at 1 block/CU).
//
// R6 = R1 grid + R2/R5 swapped-operand vectorized inner code, persistence
// REMOVED. R4/R5's persistent 16-window loop + register prefetch correlated
// with a 16x FETCH explosion (77 MB -> 2.4 GB, BW-bound at 2.4 TB/s) that no
// weights/bias/x re-fetch accounting explains; this round isolates the epilogue
// vectorization from that machinery.
//
// Inner-code techniques (vs R1):
//  - Q/K proj swapped: D = W^T·X^T -> C-frag has 4 contiguous d per lane ->
//    short4v LDS stores (was 48 scalar ds_write_b16 per wave).
//  - QK^T swapped: mfma(K,Q) = S^T -> lane holds 16 scores of ONE query;
//    softmax reduce = 2 shfl_xor (was 32 shfl ops); P write = 4 short4v.
//  - PV swapped: mfma(V^T, P^T) = O^T -> short4v O stores.
//  - out-proj swapped: mfma(Wo^T, O^T) -> float4 global stores.
//  - Q/K/V pad rows (token/key >= 49) zeroed at the phase-2 store (R4 fix):
//    X LDS rows 49..63 are uninitialized garbage; the -inf mask add in phase 3
//    must never meet NaN/Inf.
//
// Layout facts used (verified per guide):
//   A-frag: lane holds A[m=lane&15][k=(lane>>4)*8 + j], j=0..7 (16B contig)
//   B-frag: lane holds B[k=(lane>>4)*8 + j][n=lane&15]
//   C/D   : lane holds D[m=(lane>>4)*4 + r][n=lane&15], r=0..3
// Mask quirk: reference repeats mask by batch (scores[b*64+w] gets mask[b]).

typedef __attribute__((ext_vector_type(8))) short bf16x8;
typedef __attribute__((ext_vector_type(4))) short short4v;
typedef __attribute__((ext_vector_type(4))) float f32x4;

__device__ __forceinline__ short f2bf(float x) {
  unsigned u = __builtin_bit_cast(unsigned, x);
  u += 0x7fffu + ((u >> 16) & 1u);   // RNE
  return (short)(u >> 16);
}

// ---------------- prep: weight transpose->bf16, bias expansion ----------------
__global__ void prep_kernel(const float* __restrict__ wq, const float* __restrict__ wk,
                            const float* __restrict__ wv, const float* __restrict__ wo,
                            const float* __restrict__ table,
                            short* __restrict__ wT, float* __restrict__ biasx) {
  int tid = blockIdx.x * 256 + threadIdx.x;
  if (tid < 4 * 36864) {
    int mat = tid / 36864, rem = tid % 36864;
    int k = rem / 192, n = rem % 192;
    const float* w = (mat == 0) ? wq : (mat == 1) ? wk : (mat == 2) ? wv : wo;
    wT[mat * 36864 + n * 192 + k] = f2bf(w[k * 192 + n]);
  }
  if (tid < 6 * 2401) {
    int h = tid / 2401, rem = tid % 2401;
    int q = rem / 49, k = rem % 49;
    int idx = ((q / 7) - (k / 7) + 6) * 13 + ((q % 7) - (k % 7) + 6);
    biasx[tid] = table[idx * 6 + h];
  }
}

// ---------------- main fused kernel ----------------
__launch_bounds__(768, 3)
__global__ void swin_attn_kernel(const float* __restrict__ x,
                                 const short* __restrict__ wT,
                                 const float* __restrict__ biasx,
                                 const float* __restrict__ bq, const float* __restrict__ bk,
                                 const float* __restrict__ bv, const float* __restrict__ bo,
                                 float* __restrict__ out) {
  extern __shared__ short smem[];
  short* s_xo = smem;           // 64 x 200 (X, then O after phase 3)
  short* s_q  = smem + 12800;   // 64 x 200
  short* s_k  = smem + 25600;   // 64 x 200
  short* s_vt = smem + 38400;   // 192 x 72 (V transposed: [d][key])
  short* s_p  = smem + 52224;   // 12 waves x 16 x 72 (private P strips)
  // total = 66048 shorts = 132096 B (1 block/CU)

  const int tid  = threadIdx.x;
  const int w    = tid >> 6;       // wave id 0..11
  const int lane = tid & 63;
  const int quad = lane >> 4;
  const int l15  = lane & 15;

  const int bw  = blockIdx.x;
  const int b   = bw >> 6;          // batch
  const int wi  = bw & 63;          // window in image
  const int wwh = wi >> 3, www = wi & 7;   // spatial window coords
  const int mwh = b >> 3,  mww = b & 7;    // mask window coords (reference quirk!)

  const int rt = w & 3;   // token/query/key row-tile owned by this wave
  const int g  = w >> 2;  // dout-third (ph2/ph4) == head-pair (ph3)

  const f32x4 zero4 = {0.f, 0.f, 0.f, 0.f};
  const float NEGINF = -__builtin_inff();
  const float SCALE = 0.17677669529663687f;  // 1/sqrt(32)

  // token owned in ph2 Q/K store and ph4 (swapped layouts): rt*16 + l15
  const int token = rt * 16 + l15;
  const bool tokv = (token < 49);

  // ---- phase-3 mask-add term (16 regs): {0, -1000, -inf} ----
  // for query = rt*16+l15, key = mt*16+quad*4+r.
  const int qc  = tokv ? token : 48;
  const int qth = qc / 7, qtw = qc - qth * 7;
  const int cq  = ((mwh == 7) ? (1 + (qth >= 4)) : 0) * 3
                + ((mww == 7) ? (1 + (qtw >= 4)) : 0);
  float bmadd[4][4];
#pragma unroll
  for (int mt = 0; mt < 4; ++mt) {
#pragma unroll
    for (int r = 0; r < 4; ++r) {
      int key = mt * 16 + quad * 4 + r;
      if (key > 48) {
        bmadd[mt][r] = NEGINF;
      } else {
        int kth = key / 7, ktw = key - kth * 7;
        int ck = ((mwh == 7) ? (1 + (kth >= 4)) : 0) * 3
               + ((mww == 7) ? (1 + (ktw >= 4)) : 0);
        bmadd[mt][r] = (ck == cq) ? 0.f : -1000.f;
      }
    }
  }

  // ---- phase 1: load shifted window x -> LDS bf16 ----
  {
    const int hb = wwh * 7 + 3, wb = www * 7 + 3;
    for (int i = tid; i < 2352; i += 768) {
      int t = i / 48, c4 = i - t * 48;
      int th = t / 7, tw = t - th * 7;
      int gh = hb + th; if (gh >= 56) gh -= 56;
      int gw = wb + tw; if (gw >= 56) gw -= 56;
      float4 v = *(const float4*)(x + (((b * 56 + gh) * 56 + gw) * 192 + c4 * 4));
      short4v s;
      s[0] = f2bf(v.x); s[1] = f2bf(v.y); s[2] = f2bf(v.z); s[3] = f2bf(v.w);
      *(short4v*)(s_xo + t * 200 + c4 * 4) = s;
    }
  }
  __syncthreads();

  // ---- phase 2: QKV projections ----
  {
    bf16x8 xf[6];
#pragma unroll
    for (int ks = 0; ks < 6; ++ks)
      xf[ks] = *(const bf16x8*)(s_xo + (rt * 16 + l15) * 200 + ks * 32 + quad * 8);

    // Q, K swapped: D[m=dout][n=token] = W^T · X^T -> short4v stores.
    // Pad tokens (>=49) store 0 (X rows 49..63 are garbage; keep ph3 NaN-free).
#pragma unroll
    for (int mat = 0; mat < 2; ++mat) {
      const short* wt = wT + mat * 36864;
      const float* bp = mat ? bk : bq;
      short* dst = mat ? s_k : s_q;
#pragma unroll
      for (int j = 0; j < 4; ++j) {
        const int dbase = (g * 4 + j) * 16;
        const short* wrow = wt + (dbase + l15) * 192;
        f32x4 acc = zero4;
#pragma unroll
        for (int ks = 0; ks < 6; ++ks) {
          bf16x8 wfr = *(const bf16x8*)(wrow + ks * 32 + quad * 8);
          acc = __builtin_amdgcn_mfma_f32_16x16x32_bf16(wfr, xf[ks], acc, 0, 0, 0);
        }
        const float4 b4 = *(const float4*)(bp + dbase + quad * 4);
        short4v st;
        st[0] = f2bf(tokv ? acc[0] + b4.x : 0.f);
        st[1] = f2bf(tokv ? acc[1] + b4.y : 0.f);
        st[2] = f2bf(tokv ? acc[2] + b4.z : 0.f);
        st[3] = f2bf(tokv ? acc[3] + b4.w : 0.f);
        *(short4v*)(dst + (rt * 16 + l15) * 200 + dbase + quad * 4) = st;
      }
    }
    // V unswapped: D[m=key][n=dout] -> short4v stores into VT[d][key].
    {
      const short* wt = wT + 2 * 36864;
#pragma unroll
      for (int j = 0; j < 4; ++j) {
        const int dbase = (g * 4 + j) * 16;
        const short* wrow = wt + (dbase + l15) * 192;
        f32x4 acc = zero4;
#pragma unroll
        for (int ks = 0; ks < 6; ++ks) {
          bf16x8 wfr = *(const bf16x8*)(wrow + ks * 32 + quad * 8);
          acc = __builtin_amdgcn_mfma_f32_16x16x32_bf16(xf[ks], wfr, acc, 0, 0, 0);
        }
        const float bvv = bv[dbase + l15];
        short4v st;
#pragma unroll
        for (int r = 0; r < 4; ++r) {
          int key = rt * 16 + quad * 4 + r;
          st[r] = f2bf((key < 49) ? (acc[r] + bvv) : 0.f);   // zero pad keys
        }
        *(short4v*)(s_vt + (dbase + l15) * 72 + rt * 16 + quad * 4) = st;
      }
    }
  }
  __syncthreads();   // B1: QKV ready; X dead

  // ---- phase 3: attention (wave = query-tile rt x head-pair g) ----
  short* myp = s_p + w * 1152;   // wave-private 16x72 P strip
#pragma unroll
  for (int hh = 0; hh < 2; ++hh) {
    const int h = g * 2 + hh;
    const int d0 = h * 32;
    const float* bx = biasx + h * 2401 + qc * 49;
    // swapped QK^T: S^T[key][query] = mfma(A=K rows, B=Q^T)
    bf16x8 qf = *(const bf16x8*)(s_q + (rt * 16 + l15) * 200 + d0 + quad * 8);
    float sv[4][4];
#pragma unroll
    for (int mt = 0; mt < 4; ++mt) {
      bf16x8 kf = *(const bf16x8*)(s_k + (mt * 16 + l15) * 200 + d0 + quad * 8);
      f32x4 s = __builtin_amdgcn_mfma_f32_16x16x32_bf16(kf, qf, zero4, 0, 0, 0);
#pragma unroll
      for (int r = 0; r < 4; ++r) {
        // clamp bias addr for pad keys (mt==3 only); value irrelevant there
        // because bmadd = -inf and all operands stay finite.
        int key = mt * 16 + quad * 4 + r;
        int kc = (mt < 3) ? key : (((quad * 4 + r) == 0) ? 48 : 0);
        sv[mt][r] = s[r] * SCALE + bx[kc] + bmadd[mt][r];
      }
    }
    // softmax for query l15: 16 lane-local values, reduce across quads (2 shfl)
    float mx = sv[0][0];
#pragma unroll
    for (int mt = 0; mt < 4; ++mt)
#pragma unroll
      for (int r = 0; r < 4; ++r) mx = fmaxf(mx, sv[mt][r]);
    mx = fmaxf(mx, __shfl_xor(mx, 16));
    mx = fmaxf(mx, __shfl_xor(mx, 32));
    float s0 = 0.f;
#pragma unroll
    for (int mt = 0; mt < 4; ++mt)
#pragma unroll
      for (int r = 0; r < 4; ++r) {
        float e = __expf(sv[mt][r] - mx);
        sv[mt][r] = e;
        s0 += e;
      }
    s0 += __shfl_xor(s0, 16);
    s0 += __shfl_xor(s0, 32);
    const float inv = 1.0f / s0;   // normalization folded into O epilogue
    // P -> LDS (unnormalized, bf16). Same-wave LDS RAW: DS in wave order.
#pragma unroll
    for (int mt = 0; mt < 4; ++mt) {
      short4v st;
#pragma unroll
      for (int r = 0; r < 4; ++r) st[r] = f2bf(sv[mt][r]);
      *(short4v*)(myp + l15 * 72 + mt * 16 + quad * 4) = st;
    }
    // swapped PV: O^T[d][query] = mfma(A=V^T rows, B=P^T)
#pragma unroll
    for (int mt2 = 0; mt2 < 2; ++mt2) {
      f32x4 o = zero4;
#pragma unroll
      for (int ks = 0; ks < 2; ++ks) {
        bf16x8 vfr = *(const bf16x8*)(s_vt + (d0 + mt2 * 16 + l15) * 72 + ks * 32 + quad * 8);
        bf16x8 pfr = *(const bf16x8*)(myp + l15 * 72 + ks * 32 + quad * 8);
        o = __builtin_amdgcn_mfma_f32_16x16x32_bf16(vfr, pfr, o, 0, 0, 0);
      }
      short4v st;
#pragma unroll
      for (int r = 0; r < 4; ++r) st[r] = f2bf(o[r] * inv);
      *(short4v*)(s_xo + (rt * 16 + l15) * 200 + d0 + mt2 * 16 + quad * 4) = st;
    }
  }
  __syncthreads();   // B2: O ready (cross-wave)

  // ---- phase 4: out projection (swapped) ----
  bf16x8 ao[6];
#pragma unroll
  for (int ks = 0; ks < 6; ++ks)
    ao[ks] = *(const bf16x8*)(s_xo + (rt * 16 + l15) * 200 + ks * 32 + quad * 8);

  int rowbase = 0;
  if (tokv) {
    int tth = token / 7, ttw = token - tth * 7;
    int gh = wwh * 7 + tth + 3; if (gh >= 56) gh -= 56;
    int gw = www * 7 + ttw + 3; if (gw >= 56) gw -= 56;
    rowbase = ((b * 56 + gh) * 56 + gw) * 192;
  }
  const short* wto = wT + 3 * 36864;
#pragma unroll
  for (int j = 0; j < 4; ++j) {
    const int cbase = (g * 4 + j) * 16;
    const short* wrow = wto + (cbase + l15) * 192;
    f32x4 acc = zero4;
#pragma unroll
    for (int ks = 0; ks < 6; ++ks) {
      bf16x8 wfr = *(const bf16x8*)(wrow + ks * 32 + quad * 8);
      acc = __builtin_amdgcn_mfma_f32_16x16x32_bf16(wfr, ao[ks], acc, 0, 0, 0);
    }
    const float4 b4 = *(const float4*)(bo + cbase + quad * 4);
    if (tokv) {
      float4 v;
      v.x = acc[0] + b4.x; v.y = acc[1] + b4.y;
      v.z = acc[2] + b4.z; v.w = acc[3] + b4.w;
      *(float4*)(out + rowbase + cbase + quad * 4) = v;
    }
  }
}

extern "C" void kernel_launch(void* const* d_in, const int* in_sizes, int n_in,
                              void* d_out, int out_size, void* d_ws, size_t ws_size,
                              hipStream_t stream) {
  const float* x     = (const float*)d_in[0];
  const float* table = (const float*)d_in[1];
  const float* wq    = (const float*)d_in[2];
  const float* bq    = (const float*)d_in[3];
  const float* wk    = (const float*)d_in[4];
  const float* bk    = (const float*)d_in[5];
  const float* wv    = (const float*)d_in[6];
  const float* bv    = (const float*)d_in[7];
  const float* wo    = (const float*)d_in[8];
  const float* bo    = (const float*)d_in[9];
  float* out = (float*)d_out;

  short* wT    = (short*)d_ws;                       // 294912 B
  float* biasx = (float*)((char*)d_ws + 294912);     // 57624 B

  prep_kernel<<<576, 256, 0, stream>>>(wq, wk, wv, wo, table, wT, biasx);

  const int smem_bytes = 66048 * 2;  // 132096
  (void)hipFuncSetAttribute(reinterpret_cast<const void*>(swin_attn_kernel),
                            hipFuncAttributeMaxDynamicSharedMemorySize, smem_bytes);
  swin_attn_kernel<<<4096, 768, smem_bytes, stream>>>(x, wT, biasx, bq, bk, bv, bo, out);
}

// Round 7
// 490.466 us; speedup vs baseline: 3.0168x; 1.7097x over previous
//
#include <hip/hip_runtime.h>

// Swin window attention, fused one-window-per-block (R7).
// Shapes: B=64, RES=56, DIMS=192, HEADS=6, HD=32, WS=7, N=49, nW=64, SHIFT=3.
// Grid = 4096 blocks (1 window each). Block = 768 threads (12 waves, 3/SIMD).
//
// R7 theory: R1/R6 are L2-BW-bound on redundant weight re-reads (R6: 1152 KB
// weight reads per window vs 288 KB unique). Fix: keep the swapped-operand
// vector stores (R6) but restore 4x weight reuse (R1): each weight frag gets
// 4 accumulators over the 4 token-tiles. Phase-2 partition: wave = (matrix
// g = w>>2, 3 dout-tiles jb = (w&3)*3), all 4 token-tiles. Phase-4: wave =
// 1 col-tile x 4 token-tiles. Weight traffic/window: 1152 -> 288 KB (floor).
// Bias: biasx rows padded to 52 floats (16B-aligned) -> phase-3 bias gather is
// 8 coalesced float4 loads (was 32 scattered scalar loads).
//
// Layout facts used (verified per guide):
//   A-frag: lane holds A[m=lane&15][k=(lane>>4)*8 + j], j=0..7 (16B contig)
//   B-frag: lane holds B[k=(lane>>4)*8 + j][n=lane&15]
//   C/D   : lane holds D[m=(lane>>4)*4 + r][n=lane&15], r=0..3
//   X-frag from [tok][d] LDS serves as BOTH A and B role (same lane->addr map).
// Pad rows: Q/K tokens >= 49 and V keys >= 49 zeroed at store (X LDS rows
// 49..63 are garbage; the -inf mask add in ph3 must never meet NaN/Inf).
// Mask quirk: reference repeats mask by batch (scores[b*64+w] gets mask[b]).

typedef __attribute__((ext_vector_type(8))) short bf16x8;
typedef __attribute__((ext_vector_type(4))) short short4v;
typedef __attribute__((ext_vector_type(4))) float f32x4;

__device__ __forceinline__ short f2bf(float x) {
  unsigned u = __builtin_bit_cast(unsigned, x);
  u += 0x7fffu + ((u >> 16) & 1u);   // RNE
  return (short)(u >> 16);
}

// ---------------- prep: weight transpose->bf16, bias expansion ----------------
// biasx layout: [h][49][52] f32, rows padded to 52 (16B-aligned); k=49..51 zeroed.
__global__ void prep_kernel(const float* __restrict__ wq, const float* __restrict__ wk,
                            const float* __restrict__ wv, const float* __restrict__ wo,
                            const float* __restrict__ table,
                            short* __restrict__ wT, float* __restrict__ biasx) {
  int tid = blockIdx.x * 256 + threadIdx.x;
  if (tid < 4 * 36864) {
    int mat = tid / 36864, rem = tid % 36864;
    int k = rem / 192, n = rem % 192;
    const float* w = (mat == 0) ? wq : (mat == 1) ? wk : (mat == 2) ? wv : wo;
    wT[mat * 36864 + n * 192 + k] = f2bf(w[k * 192 + n]);
  }
  if (tid < 6 * 2548) {
    int h = tid / 2548, rem = tid % 2548;
    int q = rem / 52, k = rem % 52;
    float v = 0.f;
    if (k < 49) {
      int idx = ((q / 7) - (k / 7) + 6) * 13 + ((q % 7) - (k % 7) + 6);
      v = table[idx * 6 + h];
    }
    biasx[h * 2548 + q * 52 + k] = v;
  }
}

// ---------------- main fused kernel ----------------
__launch_bounds__(768, 3)
__global__ void swin_attn_kernel(const float* __restrict__ x,
                                 const short* __restrict__ wT,
                                 const float* __restrict__ biasx,
                                 const float* __restrict__ bq, const float* __restrict__ bk,
                                 const float* __restrict__ bv, const float* __restrict__ bo,
                                 float* __restrict__ out) {
  extern __shared__ short smem[];
  short* s_xo = smem;           // 64 x 200 (X, then O after phase 3)
  short* s_q  = smem + 12800;   // 64 x 200
  short* s_k  = smem + 25600;   // 64 x 200
  short* s_vt = smem + 38400;   // 192 x 72 (V transposed: [d][key])
  short* s_p  = smem + 52224;   // 12 waves x 16 x 72 (private P strips)
  // total = 66048 shorts = 132096 B (1 block/CU)

  const int tid  = threadIdx.x;
  const int w    = tid >> 6;       // wave id 0..11
  const int lane = tid & 63;
  const int quad = lane >> 4;
  const int l15  = lane & 15;

  const int bw  = blockIdx.x;
  const int b   = bw >> 6;          // batch
  const int wi  = bw & 63;          // window in image
  const int wwh = wi >> 3, www = wi & 7;   // spatial window coords
  const int mwh = b >> 3,  mww = b & 7;    // mask window coords (reference quirk!)

  const int rt = w & 3;   // ph2: dout-tile group; ph3: query-tile; ph4 unused
  const int g  = w >> 2;  // ph2: matrix (0=Q,1=K,2=V); ph3: head-pair

  const f32x4 zero4 = {0.f, 0.f, 0.f, 0.f};
  const float NEGINF = -__builtin_inff();
  const float SCALE = 0.17677669529663687f;  // 1/sqrt(32)

  // ---- phase 1: load shifted window x -> LDS bf16 ----
  {
    const int hb = wwh * 7 + 3, wb = www * 7 + 3;
    for (int i = tid; i < 2352; i += 768) {
      int t = i / 48, c4 = i - t * 48;
      int th = t / 7, tw = t - th * 7;
      int gh = hb + th; if (gh >= 56) gh -= 56;
      int gw = wb + tw; if (gw >= 56) gw -= 56;
      float4 v = *(const float4*)(x + (((b * 56 + gh) * 56 + gw) * 192 + c4 * 4));
      short4v s;
      s[0] = f2bf(v.x); s[1] = f2bf(v.y); s[2] = f2bf(v.z); s[3] = f2bf(v.w);
      *(short4v*)(s_xo + t * 200 + c4 * 4) = s;
    }
  }
  __syncthreads();

  // ---- phase 2: QKV projections, 4x weight reuse ----
  // wave w: matrix g, dout-tiles rt*3..rt*3+2, ALL 4 token-tiles per dout-tile.
  // Each weight frag is loaded exactly once per block across all waves.
  {
    bf16x8 xf[4][6];
#pragma unroll
    for (int nt = 0; nt < 4; ++nt)
#pragma unroll
      for (int ks = 0; ks < 6; ++ks)
        xf[nt][ks] = *(const bf16x8*)(s_xo + (nt * 16 + l15) * 200 + ks * 32 + quad * 8);

    const short* wtm = wT + g * 36864;
    if (g < 2) {
      // Q/K swapped: D[dout][token] = mfma(A=W^T rows, B=X^T). Vector stores to
      // [tok][d] (4 consecutive d per lane). Pad tokens store 0.
      const float* bp = g ? bk : bq;
      short* dst = g ? s_k : s_q;
#pragma unroll
      for (int i = 0; i < 3; ++i) {
        const int dbase = (rt * 3 + i) * 16;
        const short* wrow = wtm + (dbase + l15) * 192;
        bf16x8 wf[6];
#pragma unroll
        for (int ks = 0; ks < 6; ++ks)
          wf[ks] = *(const bf16x8*)(wrow + ks * 32 + quad * 8);
        f32x4 acc[4] = {zero4, zero4, zero4, zero4};
#pragma unroll
        for (int ks = 0; ks < 6; ++ks)
#pragma unroll
          for (int nt = 0; nt < 4; ++nt)
            acc[nt] = __builtin_amdgcn_mfma_f32_16x16x32_bf16(wf[ks], xf[nt][ks], acc[nt], 0, 0, 0);
        const float4 b4 = *(const float4*)(bp + dbase + quad * 4);
#pragma unroll
        for (int nt = 0; nt < 4; ++nt) {
          const int tok = nt * 16 + l15;
          const bool tv = (tok < 49);
          short4v st;
          st[0] = f2bf(tv ? acc[nt][0] + b4.x : 0.f);
          st[1] = f2bf(tv ? acc[nt][1] + b4.y : 0.f);
          st[2] = f2bf(tv ? acc[nt][2] + b4.z : 0.f);
          st[3] = f2bf(tv ? acc[nt][3] + b4.w : 0.f);
          *(short4v*)(dst + tok * 200 + dbase + quad * 4) = st;
        }
      }
    } else {
      // V unswapped: D[key][dout] = mfma(A=X, B=W). Vector stores to VT[d][key]
      // (4 consecutive keys per lane). Pad keys store 0.
#pragma unroll
      for (int i = 0; i < 3; ++i) {
        const int dbase = (rt * 3 + i) * 16;
        const short* wrow = wtm + (dbase + l15) * 192;
        bf16x8 wf[6];
#pragma unroll
        for (int ks = 0; ks < 6; ++ks)
          wf[ks] = *(const bf16x8*)(wrow + ks * 32 + quad * 8);
        f32x4 acc[4] = {zero4, zero4, zero4, zero4};
#pragma unroll
        for (int ks = 0; ks < 6; ++ks)
#pragma unroll
          for (int nt = 0; nt < 4; ++nt)
            acc[nt] = __builtin_amdgcn_mfma_f32_16x16x32_bf16(xf[nt][ks], wf[ks], acc[nt], 0, 0, 0);
        const float bvv = bv[dbase + l15];
#pragma unroll
        for (int nt = 0; nt < 4; ++nt) {
          short4v st;
#pragma unroll
          for (int r = 0; r < 4; ++r) {
            int key = nt * 16 + quad * 4 + r;
            st[r] = f2bf((key < 49) ? (acc[nt][r] + bvv) : 0.f);
          }
          *(short4v*)(s_vt + (dbase + l15) * 72 + nt * 16 + quad * 4) = st;
        }
      }
    }
  }
  __syncthreads();   // B1: QKV ready; X dead

  // ---- phase 3: attention (wave = query-tile rt x head-pair g) ----
  // mask-add term (computed here: short liveness): {0, -1000, -inf} for
  // query = rt*16+l15, key = mt*16+quad*4+r.
  const int token = rt * 16 + l15;
  const int qc  = (token < 49) ? token : 48;
  {
    const int qth = qc / 7, qtw = qc - qth * 7;
    const int cq  = ((mwh == 7) ? (1 + (qth >= 4)) : 0) * 3
                  + ((mww == 7) ? (1 + (qtw >= 4)) : 0);
    float bmadd[4][4];
#pragma unroll
    for (int mt = 0; mt < 4; ++mt) {
#pragma unroll
      for (int r = 0; r < 4; ++r) {
        int key = mt * 16 + quad * 4 + r;
        if (key > 48) {
          bmadd[mt][r] = NEGINF;
        } else {
          int kth = key / 7, ktw = key - kth * 7;
          int ck = ((mwh == 7) ? (1 + (kth >= 4)) : 0) * 3
                 + ((mww == 7) ? (1 + (ktw >= 4)) : 0);
          bmadd[mt][r] = (ck == cq) ? 0.f : -1000.f;
        }
      }
    }

    short* myp = s_p + w * 1152;   // wave-private 16x72 P strip
#pragma unroll
    for (int hh = 0; hh < 2; ++hh) {
      const int h = g * 2 + hh;
      const int d0 = h * 32;
      // coalesced bias: f32x4 per (mt); row base 16B-aligned (2548,52,kc all %4==0)
      const float* bxr = biasx + h * 2548 + qc * 52;
      f32x4 b4[4];
#pragma unroll
      for (int mt = 0; mt < 4; ++mt) {
        const int kc = (mt < 3) ? (mt * 16 + quad * 4) : 48;  // mt=3: clamp, -inf masks
        b4[mt] = *(const f32x4*)(bxr + kc);
      }
      // swapped QK^T: S^T[key][query] = mfma(A=K rows, B=Q^T)
      bf16x8 qf = *(const bf16x8*)(s_q + (rt * 16 + l15) * 200 + d0 + quad * 8);
      float sv[4][4];
#pragma unroll
      for (int mt = 0; mt < 4; ++mt) {
        bf16x8 kf = *(const bf16x8*)(s_k + (mt * 16 + l15) * 200 + d0 + quad * 8);
        f32x4 s = __builtin_amdgcn_mfma_f32_16x16x32_bf16(kf, qf, zero4, 0, 0, 0);
#pragma unroll
        for (int r = 0; r < 4; ++r)
          sv[mt][r] = s[r] * SCALE + b4[mt][r] + bmadd[mt][r];
      }
      // softmax for query l15: 16 lane-local values, reduce across quads (2 shfl)
      float mx = sv[0][0];
#pragma unroll
      for (int mt = 0; mt < 4; ++mt)
#pragma unroll
        for (int r = 0; r < 4; ++r) mx = fmaxf(mx, sv[mt][r]);
      mx = fmaxf(mx, __shfl_xor(mx, 16));
      mx = fmaxf(mx, __shfl_xor(mx, 32));
      float s0 = 0.f;
#pragma unroll
      for (int mt = 0; mt < 4; ++mt)
#pragma unroll
        for (int r = 0; r < 4; ++r) {
          float e = __expf(sv[mt][r] - mx);
          sv[mt][r] = e;
          s0 += e;
        }
      s0 += __shfl_xor(s0, 16);
      s0 += __shfl_xor(s0, 32);
      const float inv = 1.0f / s0;   // normalization folded into O epilogue
      // P -> LDS (unnormalized, bf16). Same-wave LDS RAW: DS in wave order.
#pragma unroll
      for (int mt = 0; mt < 4; ++mt) {
        short4v st;
#pragma unroll
        for (int r = 0; r < 4; ++r) st[r] = f2bf(sv[mt][r]);
        *(short4v*)(myp + l15 * 72 + mt * 16 + quad * 4) = st;
      }
      // swapped PV: O^T[d][query] = mfma(A=V^T rows, B=P^T)
#pragma unroll
      for (int mt2 = 0; mt2 < 2; ++mt2) {
        f32x4 o = zero4;
#pragma unroll
        for (int ks = 0; ks < 2; ++ks) {
          bf16x8 vfr = *(const bf16x8*)(s_vt + (d0 + mt2 * 16 + l15) * 72 + ks * 32 + quad * 8);
          bf16x8 pfr = *(const bf16x8*)(myp + l15 * 72 + ks * 32 + quad * 8);
          o = __builtin_amdgcn_mfma_f32_16x16x32_bf16(vfr, pfr, o, 0, 0, 0);
        }
        short4v st;
#pragma unroll
        for (int r = 0; r < 4; ++r) st[r] = f2bf(o[r] * inv);
        *(short4v*)(s_xo + (rt * 16 + l15) * 200 + d0 + mt2 * 16 + quad * 4) = st;
      }
    }
  }
  __syncthreads();   // B2: O ready (cross-wave)

  // ---- phase 4: out projection (swapped), 4x weight reuse ----
  // wave w: col-tile w (16 cols), ALL 4 token-tiles. Weight frags read once.
  {
    bf16x8 ao[4][6];
#pragma unroll
    for (int nt = 0; nt < 4; ++nt)
#pragma unroll
      for (int ks = 0; ks < 6; ++ks)
        ao[nt][ks] = *(const bf16x8*)(s_xo + (nt * 16 + l15) * 200 + ks * 32 + quad * 8);

    const int cbase = w * 16;
    const short* wrow = wT + 3 * 36864 + (cbase + l15) * 192;
    bf16x8 wf[6];
#pragma unroll
    for (int ks = 0; ks < 6; ++ks)
      wf[ks] = *(const bf16x8*)(wrow + ks * 32 + quad * 8);
    f32x4 acc[4] = {zero4, zero4, zero4, zero4};
#pragma unroll
    for (int ks = 0; ks < 6; ++ks)
#pragma unroll
      for (int nt = 0; nt < 4; ++nt)
        acc[nt] = __builtin_amdgcn_mfma_f32_16x16x32_bf16(wf[ks], ao[nt][ks], acc[nt], 0, 0, 0);

    const float4 bo4 = *(const float4*)(bo + cbase + quad * 4);
#pragma unroll
    for (int nt = 0; nt < 4; ++nt) {
      const int tok = nt * 16 + l15;
      if (tok < 49) {
        int tth = tok / 7, ttw = tok - tth * 7;
        int gh = wwh * 7 + tth + 3; if (gh >= 56) gh -= 56;
        int gw = www * 7 + ttw + 3; if (gw >= 56) gw -= 56;
        float4 v;
        v.x = acc[nt][0] + bo4.x; v.y = acc[nt][1] + bo4.y;
        v.z = acc[nt][2] + bo4.z; v.w = acc[nt][3] + bo4.w;
        *(float4*)(out + ((b * 56 + gh) * 56 + gw) * 192 + cbase + quad * 4) = v;
      }
    }
  }
}

extern "C" void kernel_launch(void* const* d_in, const int* in_sizes, int n_in,
                              void* d_out, int out_size, void* d_ws, size_t ws_size,
                              hipStream_t stream) {
  const float* x     = (const float*)d_in[0];
  const float* table = (const float*)d_in[1];
  const float* wq    = (const float*)d_in[2];
  const float* bq    = (const float*)d_in[3];
  const float* wk    = (const float*)d_in[4];
  const float* bk    = (const float*)d_in[5];
  const float* wv    = (const float*)d_in[6];
  const float* bv    = (const float*)d_in[7];
  const float* wo    = (const float*)d_in[8];
  const float* bo    = (const float*)d_in[9];
  float* out = (float*)d_out;

  short* wT    = (short*)d_ws;                       // 294912 B
  float* biasx = (float*)((char*)d_ws + 294912);     // 6*2548*4 = 61152 B

  prep_kernel<<<576, 256, 0, stream>>>(wq, wk, wv, wo, table, wT, biasx);

  const int smem_bytes = 66048 * 2;  // 132096
  (void)hipFuncSetAttribute(reinterpret_cast<const void*>(swin_attn_kernel),
                            hipFuncAttributeMaxDynamicSharedMemorySize, smem_bytes);
  swin_attn_kernel<<<4096, 768, smem_bytes, stream>>>(x, wT, biasx, bq, bk, bv, bo, out);
}

// Round 8
// 480.394 us; speedup vs baseline: 3.0801x; 1.0210x over previous
//
#include <hip/hip_runtime.h>

// Swin window attention, fused one-window-per-block (R8).
// Shapes: B=64, RES=56, DIMS=192, HEADS=6, HD=32, WS=7, N=49, nW=64, SHIFT=3.
// Grid = 4096 blocks (1 window each). Block = 768 threads (12 waves, 3/SIMD).
//
// R8 vs R7 (structure unchanged: 4x weight reuse, swapped-operand vector
// epilogues, FETCH 77 MB):
//  1. All f32->bf16 conversions via v_cvt_pk_bf16_f32 inline asm (1 op per 2
//     values) replacing manual-RNE f2bf (~5 ops/value). ~450 VALU ops/thread
//     saved. (T12 recipe: no builtin on gfx950.)
//  2. Phase-4 weight frags prefetched BEFORE the B2 barrier (independent of
//     LDS O) -> L2 latency hides under barrier wait.
//  3. s_setprio(1) around ph2/ph4 MFMA clusters (wave role diversity exists:
//     Q/K/V matrix split + barrier skew).
//
// R7: restored 4x weight reuse (wave = matrix x 3 dout-tiles, 4 accumulators
// over token-tiles; weight frags loaded once per block) -> L2 weight traffic
// 1152->288 KB/window. Bias rows padded to 52 f32 -> coalesced f32x4 gathers.
//
// Layout facts used (verified per guide):
//   A-frag: lane holds A[m=lane&15][k=(lane>>4)*8 + j], j=0..7 (16B contig)
//   B-frag: lane holds B[k=(lane>>4)*8 + j][n=lane&15]
//   C/D   : lane holds D[m=(lane>>4)*4 + r][n=lane&15], r=0..3
//   X-frag from [tok][d] LDS serves as BOTH A and B role (same lane->addr map).
// Pad rows: Q/K tokens >= 49 and V keys >= 49 zeroed at store (X LDS rows
// 49..63 are garbage; the -inf mask add in ph3 must never meet NaN/Inf).
// Mask quirk: reference repeats mask by batch (scores[b*64+w] gets mask[b]).

typedef __attribute__((ext_vector_type(8))) short bf16x8;
typedef __attribute__((ext_vector_type(4))) short short4v;
typedef __attribute__((ext_vector_type(4))) float f32x4;

__device__ __forceinline__ short f2bf(float x) {
  unsigned u = __builtin_bit_cast(unsigned, x);
  u += 0x7fffu + ((u >> 16) & 1u);   // RNE
  return (short)(u >> 16);
}

// packed f32x2 -> bf16x2 (RNE), 1 VALU op. No builtin on gfx950 (T12).
__device__ __forceinline__ unsigned cvtpk(float a, float b) {
  unsigned r;
  asm("v_cvt_pk_bf16_f32 %0, %1, %2" : "=v"(r) : "v"(a), "v"(b));
  return r;
}

// ---------------- prep: weight transpose->bf16, bias expansion ----------------
// biasx layout: [h][49][52] f32, rows padded to 52 (16B-aligned); k=49..51 zeroed.
__global__ void prep_kernel(const float* __restrict__ wq, const float* __restrict__ wk,
                            const float* __restrict__ wv, const float* __restrict__ wo,
                            const float* __restrict__ table,
                            short* __restrict__ wT, float* __restrict__ biasx) {
  int tid = blockIdx.x * 256 + threadIdx.x;
  if (tid < 4 * 36864) {
    int mat = tid / 36864, rem = tid % 36864;
    int k = rem / 192, n = rem % 192;
    const float* w = (mat == 0) ? wq : (mat == 1) ? wk : (mat == 2) ? wv : wo;
    wT[mat * 36864 + n * 192 + k] = f2bf(w[k * 192 + n]);
  }
  if (tid < 6 * 2548) {
    int h = tid / 2548, rem = tid % 2548;
    int q = rem / 52, k = rem % 52;
    float v = 0.f;
    if (k < 49) {
      int idx = ((q / 7) - (k / 7) + 6) * 13 + ((q % 7) - (k % 7) + 6);
      v = table[idx * 6 + h];
    }
    biasx[h * 2548 + q * 52 + k] = v;
  }
}

// ---------------- main fused kernel ----------------
__launch_bounds__(768, 3)
__global__ void swin_attn_kernel(const float* __restrict__ x,
                                 const short* __restrict__ wT,
                                 const float* __restrict__ biasx,
                                 const float* __restrict__ bq, const float* __restrict__ bk,
                                 const float* __restrict__ bv, const float* __restrict__ bo,
                                 float* __restrict__ out) {
  extern __shared__ short smem[];
  short* s_xo = smem;           // 64 x 200 (X, then O after phase 3)
  short* s_q  = smem + 12800;   // 64 x 200
  short* s_k  = smem + 25600;   // 64 x 200
  short* s_vt = smem + 38400;   // 192 x 72 (V transposed: [d][key])
  short* s_p  = smem + 52224;   // 12 waves x 16 x 72 (private P strips)
  // total = 66048 shorts = 132096 B (1 block/CU)

  const int tid  = threadIdx.x;
  const int w    = tid >> 6;       // wave id 0..11
  const int lane = tid & 63;
  const int quad = lane >> 4;
  const int l15  = lane & 15;

  const int bw  = blockIdx.x;
  const int b   = bw >> 6;          // batch
  const int wi  = bw & 63;          // window in image
  const int wwh = wi >> 3, www = wi & 7;   // spatial window coords
  const int mwh = b >> 3,  mww = b & 7;    // mask window coords (reference quirk!)

  const int rt = w & 3;   // ph2: dout-tile group; ph3: query-tile
  const int g  = w >> 2;  // ph2: matrix (0=Q,1=K,2=V); ph3: head-pair

  const f32x4 zero4 = {0.f, 0.f, 0.f, 0.f};
  const float NEGINF = -__builtin_inff();
  const float SCALE = 0.17677669529663687f;  // 1/sqrt(32)

  // ---- phase 1: load shifted window x -> LDS bf16 ----
  {
    const int hb = wwh * 7 + 3, wb = www * 7 + 3;
    for (int i = tid; i < 2352; i += 768) {
      int t = i / 48, c4 = i - t * 48;
      int th = t / 7, tw = t - th * 7;
      int gh = hb + th; if (gh >= 56) gh -= 56;
      int gw = wb + tw; if (gw >= 56) gw -= 56;
      float4 v = *(const float4*)(x + (((b * 56 + gh) * 56 + gw) * 192 + c4 * 4));
      uint2 s;
      s.x = cvtpk(v.x, v.y); s.y = cvtpk(v.z, v.w);
      *(uint2*)(s_xo + t * 200 + c4 * 4) = s;
    }
  }
  __syncthreads();

  // ---- phase 2: QKV projections, 4x weight reuse ----
  // wave w: matrix g, dout-tiles rt*3..rt*3+2, ALL 4 token-tiles per dout-tile.
  {
    bf16x8 xf[4][6];
#pragma unroll
    for (int nt = 0; nt < 4; ++nt)
#pragma unroll
      for (int ks = 0; ks < 6; ++ks)
        xf[nt][ks] = *(const bf16x8*)(s_xo + (nt * 16 + l15) * 200 + ks * 32 + quad * 8);

    const short* wtm = wT + g * 36864;
    if (g < 2) {
      // Q/K swapped: D[dout][token] = mfma(A=W^T rows, B=X^T). Vector stores to
      // [tok][d] (4 consecutive d per lane). Pad tokens store 0.
      const float* bp = g ? bk : bq;
      short* dst = g ? s_k : s_q;
#pragma unroll
      for (int i = 0; i < 3; ++i) {
        const int dbase = (rt * 3 + i) * 16;
        const short* wrow = wtm + (dbase + l15) * 192;
        bf16x8 wf[6];
#pragma unroll
        for (int ks = 0; ks < 6; ++ks)
          wf[ks] = *(const bf16x8*)(wrow + ks * 32 + quad * 8);
        f32x4 acc[4] = {zero4, zero4, zero4, zero4};
        __builtin_amdgcn_s_setprio(1);
#pragma unroll
        for (int ks = 0; ks < 6; ++ks)
#pragma unroll
          for (int nt = 0; nt < 4; ++nt)
            acc[nt] = __builtin_amdgcn_mfma_f32_16x16x32_bf16(wf[ks], xf[nt][ks], acc[nt], 0, 0, 0);
        __builtin_amdgcn_s_setprio(0);
        const float4 b4 = *(const float4*)(bp + dbase + quad * 4);
#pragma unroll
        for (int nt = 0; nt < 4; ++nt) {
          const int tok = nt * 16 + l15;
          const bool tv = (tok < 49);
          float e0 = tv ? acc[nt][0] + b4.x : 0.f;
          float e1 = tv ? acc[nt][1] + b4.y : 0.f;
          float e2 = tv ? acc[nt][2] + b4.z : 0.f;
          float e3 = tv ? acc[nt][3] + b4.w : 0.f;
          uint2 st;
          st.x = cvtpk(e0, e1); st.y = cvtpk(e2, e3);
          *(uint2*)(dst + tok * 200 + dbase + quad * 4) = st;
        }
      }
    } else {
      // V unswapped: D[key][dout] = mfma(A=X, B=W). Vector stores to VT[d][key]
      // (4 consecutive keys per lane). Pad keys store 0.
#pragma unroll
      for (int i = 0; i < 3; ++i) {
        const int dbase = (rt * 3 + i) * 16;
        const short* wrow = wtm + (dbase + l15) * 192;
        bf16x8 wf[6];
#pragma unroll
        for (int ks = 0; ks < 6; ++ks)
          wf[ks] = *(const bf16x8*)(wrow + ks * 32 + quad * 8);
        f32x4 acc[4] = {zero4, zero4, zero4, zero4};
        __builtin_amdgcn_s_setprio(1);
#pragma unroll
        for (int ks = 0; ks < 6; ++ks)
#pragma unroll
          for (int nt = 0; nt < 4; ++nt)
            acc[nt] = __builtin_amdgcn_mfma_f32_16x16x32_bf16(xf[nt][ks], wf[ks], acc[nt], 0, 0, 0);
        __builtin_amdgcn_s_setprio(0);
        const float bvv = bv[dbase + l15];
#pragma unroll
        for (int nt = 0; nt < 4; ++nt) {
          float e[4];
#pragma unroll
          for (int r = 0; r < 4; ++r) {
            int key = nt * 16 + quad * 4 + r;
            e[r] = (key < 49) ? (acc[nt][r] + bvv) : 0.f;
          }
          uint2 st;
          st.x = cvtpk(e[0], e[1]); st.y = cvtpk(e[2], e[3]);
          *(uint2*)(s_vt + (dbase + l15) * 72 + nt * 16 + quad * 4) = st;
        }
      }
    }
  }
  __syncthreads();   // B1: QKV ready; X dead

  // ---- phase 3: attention (wave = query-tile rt x head-pair g) ----
  const int token = rt * 16 + l15;
  const int qc  = (token < 49) ? token : 48;
  {
    const int qth = qc / 7, qtw = qc - qth * 7;
    const int cq  = ((mwh == 7) ? (1 + (qth >= 4)) : 0) * 3
                  + ((mww == 7) ? (1 + (qtw >= 4)) : 0);
    float bmadd[4][4];
#pragma unroll
    for (int mt = 0; mt < 4; ++mt) {
#pragma unroll
      for (int r = 0; r < 4; ++r) {
        int key = mt * 16 + quad * 4 + r;
        if (key > 48) {
          bmadd[mt][r] = NEGINF;
        } else {
          int kth = key / 7, ktw = key - kth * 7;
          int ck = ((mwh == 7) ? (1 + (kth >= 4)) : 0) * 3
                 + ((mww == 7) ? (1 + (ktw >= 4)) : 0);
          bmadd[mt][r] = (ck == cq) ? 0.f : -1000.f;
        }
      }
    }

    short* myp = s_p + w * 1152;   // wave-private 16x72 P strip
#pragma unroll
    for (int hh = 0; hh < 2; ++hh) {
      const int h = g * 2 + hh;
      const int d0 = h * 32;
      // coalesced bias: f32x4 per mt; row base 16B-aligned (2548,52,kc all %4==0)
      const float* bxr = biasx + h * 2548 + qc * 52;
      f32x4 b4[4];
#pragma unroll
      for (int mt = 0; mt < 4; ++mt) {
        const int kc = (mt < 3) ? (mt * 16 + quad * 4) : 48;  // mt=3: clamp, -inf masks
        b4[mt] = *(const f32x4*)(bxr + kc);
      }
      // swapped QK^T: S^T[key][query] = mfma(A=K rows, B=Q^T)
      bf16x8 qf = *(const bf16x8*)(s_q + (rt * 16 + l15) * 200 + d0 + quad * 8);
      float sv[4][4];
#pragma unroll
      for (int mt = 0; mt < 4; ++mt) {
        bf16x8 kf = *(const bf16x8*)(s_k + (mt * 16 + l15) * 200 + d0 + quad * 8);
        f32x4 s = __builtin_amdgcn_mfma_f32_16x16x32_bf16(kf, qf, zero4, 0, 0, 0);
#pragma unroll
        for (int r = 0; r < 4; ++r)
          sv[mt][r] = s[r] * SCALE + b4[mt][r] + bmadd[mt][r];
      }
      // softmax for query l15: 16 lane-local values, reduce across quads (2 shfl)
      float mx = sv[0][0];
#pragma unroll
      for (int mt = 0; mt < 4; ++mt)
#pragma unroll
        for (int r = 0; r < 4; ++r) mx = fmaxf(mx, sv[mt][r]);
      mx = fmaxf(mx, __shfl_xor(mx, 16));
      mx = fmaxf(mx, __shfl_xor(mx, 32));
      float s0 = 0.f;
#pragma unroll
      for (int mt = 0; mt < 4; ++mt)
#pragma unroll
        for (int r = 0; r < 4; ++r) {
          float e = __expf(sv[mt][r] - mx);
          sv[mt][r] = e;
          s0 += e;
        }
      s0 += __shfl_xor(s0, 16);
      s0 += __shfl_xor(s0, 32);
      const float inv = 1.0f / s0;   // normalization folded into O epilogue
      // P -> LDS (unnormalized, bf16). Same-wave LDS RAW: DS in wave order.
#pragma unroll
      for (int mt = 0; mt < 4; ++mt) {
        uint2 st;
        st.x = cvtpk(sv[mt][0], sv[mt][1]); st.y = cvtpk(sv[mt][2], sv[mt][3]);
        *(uint2*)(myp + l15 * 72 + mt * 16 + quad * 4) = st;
      }
      // swapped PV: O^T[d][query] = mfma(A=V^T rows, B=P^T)
#pragma unroll
      for (int mt2 = 0; mt2 < 2; ++mt2) {
        f32x4 o = zero4;
#pragma unroll
        for (int ks = 0; ks < 2; ++ks) {
          bf16x8 vfr = *(const bf16x8*)(s_vt + (d0 + mt2 * 16 + l15) * 72 + ks * 32 + quad * 8);
          bf16x8 pfr = *(const bf16x8*)(myp + l15 * 72 + ks * 32 + quad * 8);
          o = __builtin_amdgcn_mfma_f32_16x16x32_bf16(vfr, pfr, o, 0, 0, 0);
        }
        uint2 st;
        st.x = cvtpk(o[0] * inv, o[1] * inv); st.y = cvtpk(o[2] * inv, o[3] * inv);
        *(uint2*)(s_xo + (rt * 16 + l15) * 200 + d0 + mt2 * 16 + quad * 4) = st;
      }
    }
  }

  // ---- prefetch phase-4 weights BEFORE the barrier (independent of LDS O) ----
  const int cbase = w * 16;
  const short* wrow4 = wT + 3 * 36864 + (cbase + l15) * 192;
  bf16x8 wf4[6];
#pragma unroll
  for (int ks = 0; ks < 6; ++ks)
    wf4[ks] = *(const bf16x8*)(wrow4 + ks * 32 + quad * 8);

  __syncthreads();   // B2: O ready (cross-wave)

  // ---- phase 4: out projection (swapped), 4x weight reuse ----
  // wave w: col-tile w (16 cols), ALL 4 token-tiles. Weight frags read once.
  {
    bf16x8 ao[4][6];
#pragma unroll
    for (int nt = 0; nt < 4; ++nt)
#pragma unroll
      for (int ks = 0; ks < 6; ++ks)
        ao[nt][ks] = *(const bf16x8*)(s_xo + (nt * 16 + l15) * 200 + ks * 32 + quad * 8);

    f32x4 acc[4] = {zero4, zero4, zero4, zero4};
    __builtin_amdgcn_s_setprio(1);
#pragma unroll
    for (int ks = 0; ks < 6; ++ks)
#pragma unroll
      for (int nt = 0; nt < 4; ++nt)
        acc[nt] = __builtin_amdgcn_mfma_f32_16x16x32_bf16(wf4[ks], ao[nt][ks], acc[nt], 0, 0, 0);
    __builtin_amdgcn_s_setprio(0);

    const float4 bo4 = *(const float4*)(bo + cbase + quad * 4);
#pragma unroll
    for (int nt = 0; nt < 4; ++nt) {
      const int tok = nt * 16 + l15;
      if (tok < 49) {
        int tth = tok / 7, ttw = tok - tth * 7;
        int gh = wwh * 7 + tth + 3; if (gh >= 56) gh -= 56;
        int gw = www * 7 + ttw + 3; if (gw >= 56) gw -= 56;
        float4 v;
        v.x = acc[nt][0] + bo4.x; v.y = acc[nt][1] + bo4.y;
        v.z = acc[nt][2] + bo4.z; v.w = acc[nt][3] + bo4.w;
        *(float4*)(out + ((b * 56 + gh) * 56 + gw) * 192 + cbase + quad * 4) = v;
      }
    }
  }
}

extern "C" void kernel_launch(void* const* d_in, const int* in_sizes, int n_in,
                              void* d_out, int out_size, void* d_ws, size_t ws_size,
                              hipStream_t stream) {
  const float* x     = (const float*)d_in[0];
  const float* table = (const float*)d_in[1];
  const float* wq    = (const float*)d_in[2];
  const float* bq    = (const float*)d_in[3];
  const float* wk    = (const float*)d_in[4];
  const float* bk    = (const float*)d_in[5];
  const float* wv    = (const float*)d_in[6];
  const float* bv    = (const float*)d_in[7];
  const float* wo    = (const float*)d_in[8];
  const float* bo    = (const float*)d_in[9];
  float* out = (float*)d_out;

  short* wT    = (short*)d_ws;                       // 294912 B
  float* biasx = (float*)((char*)d_ws + 294912);     // 6*2548*4 = 61152 B

  prep_kernel<<<576, 256, 0, stream>>>(wq, wk, wv, wo, table, wT, biasx);

  const int smem_bytes = 66048 * 2;  // 132096
  (void)hipFuncSetAttribute(reinterpret_cast<const void*>(swin_attn_kernel),
                            hipFuncAttributeMaxDynamicSharedMemorySize, smem_bytes);
  swin_attn_kernel<<<4096, 768, smem_bytes, stream>>>(x, wT, biasx, bq, bk, bv, bo, out);
}